// Round 1
// baseline (160.484 us; speedup 1.0000x reference)
//
#include <hip/hip_runtime.h>

// ---- problem constants ----
constexpr int  Bn    = 512;
constexpr int  Dd    = 128;
constexpr int  QUEUE = 65536;
constexpr int  NEGR  = 8192;              // B*N in-batch negatives
constexpr int  NJ    = NEGR + QUEUE;      // 73728 negative columns
constexpr long long OUTC    = 1 + NJ;     // 73729 out row stride
constexpr long long MEM_OFF = 2LL * Bn * OUTC;  // new_memory offset in d_out

typedef __attribute__((ext_vector_type(8))) short  short8;
typedef __attribute__((ext_vector_type(4))) float  floatx4;

__device__ __forceinline__ unsigned short f2bf(float f) {
    union { float f; unsigned u; } x; x.f = f;
    unsigned u = x.u;
    u += 0x7fffu + ((u >> 16) & 1u);   // round-to-nearest-even
    return (unsigned short)(u >> 16);
}

__device__ __forceinline__ short8 pack8(float4 a, float4 b) {
    short8 r;
    r[0] = (short)f2bf(a.x); r[1] = (short)f2bf(a.y);
    r[2] = (short)f2bf(a.z); r[3] = (short)f2bf(a.w);
    r[4] = (short)f2bf(b.x); r[5] = (short)f2bf(b.y);
    r[6] = (short)f2bf(b.z); r[7] = (short)f2bf(b.w);
    return r;
}

// ---- kernel 0: q (512x128 f32) -> bf16 in workspace ----
__global__ void qconv(const float* __restrict__ q, unsigned short* __restrict__ qb) {
    int t = blockIdx.x * blockDim.x + threadIdx.x;      // 16384 threads, 4 elems each
    float4 v = *(const float4*)(q + (long long)t * 4);
    ushort4 r;
    r.x = f2bf(v.x); r.y = f2bf(v.y); r.z = f2bf(v.z); r.w = f2bf(v.w);
    *(ushort4*)(qb + (long long)t * 4) = r;
}

// ---- kernel 1: positive logits -> out column 0 ----
// one wave per batch row b: rows 0..511 get (q.k)/T, rows 512..1023 get mean_p(q.pos)/T
__global__ void poskern(const float* __restrict__ q, const float* __restrict__ k,
                        const float* __restrict__ ps, float* __restrict__ out) {
    int lane = threadIdx.x & 63;
    int b = blockIdx.x * (blockDim.x >> 6) + (threadIdx.x >> 6);
    if (b >= Bn) return;
    float2 qv = *(const float2*)(q + (long long)b * Dd + lane * 2);
    float2 kv = *(const float2*)(k + (long long)b * Dd + lane * 2);
    float pk = qv.x * kv.x + qv.y * kv.y;
    float pp = 0.f;
    #pragma unroll
    for (int p = 0; p < 4; ++p) {
        float2 pv = *(const float2*)(ps + ((long long)b * 4 + p) * Dd + lane * 2);
        pp += qv.x * pv.x + qv.y * pv.y;
    }
    #pragma unroll
    for (int off = 32; off; off >>= 1) {
        pk += __shfl_xor(pk, off);
        pp += __shfl_xor(pp, off);
    }
    if (lane == 0) {
        out[(long long)b * OUTC]        = pk * 10.0f;
        out[((long long)b + Bn) * OUTC] = (pp * 0.25f) * 10.0f;
    }
}

// ---- kernel 2: new_memory = memory with rows (i+index)%Q <- k_all[i] ----
__global__ void memupd(const float* __restrict__ mem, const float* __restrict__ k_all,
                       const int* __restrict__ indexp, float* __restrict__ outmem) {
    const int index = *indexp;
    const long long total = (long long)QUEUE * (Dd / 4);   // float4 chunks
    long long stride = (long long)gridDim.x * blockDim.x;
    for (long long i = blockIdx.x * (long long)blockDim.x + threadIdx.x; i < total; i += stride) {
        int row = (int)(i >> 5);          // D/4 = 32 chunks per row
        int c4  = (int)(i & 31);
        int src = (row - index) & (QUEUE - 1);
        float4 v;
        if (src < Bn) v = *(const float4*)(k_all + (long long)src * Dd + c4 * 4);
        else          v = *(const float4*)(mem   + (long long)row * Dd + c4 * 4);
        *(float4*)(outmem + (long long)row * Dd + c4 * 4) = v;
    }
}

// ---- kernel 3: l_neg = q @ [negs; memory]^T via bf16 MFMA, written twice, /TEMP ----
// block: 256 threads (4 waves). Each wave owns 16 j-columns; loops 32 M-tiles of 16.
__global__ __launch_bounds__(256) void gemm_neg(const unsigned short* __restrict__ qb,
                                                const float* __restrict__ negs,
                                                const float* __restrict__ mem,
                                                float* __restrict__ out) {
    const int lane = threadIdx.x & 63;
    const int wave = threadIdx.x >> 6;
    const int l16  = lane & 15;
    const int kg   = lane >> 4;        // 0..3
    const int klo  = kg * 8;
    const long long jbase = (long long)blockIdx.x * 64 + wave * 16;
    const long long jrow  = jbase + l16;
    const float* src = (jrow < NEGR) ? (negs + jrow * Dd)
                                     : (mem + (jrow - NEGR) * Dd);

    // B fragments for this wave's 16 columns: negmem[j][k], k = klo + s*32 .. +7
    short8 bfrag[4];
    #pragma unroll
    for (int s = 0; s < 4; ++s) {
        float4 x = *(const float4*)(src + s * 32 + klo);
        float4 y = *(const float4*)(src + s * 32 + klo + 4);
        bfrag[s] = pack8(x, y);
    }

    const long long colw = 1 + jbase + l16;   // out column for C-write (col = lane&15)

    #pragma unroll 1
    for (int m = 0; m < 32; ++m) {
        const unsigned short* arow = qb + (long long)(m * 16 + l16) * Dd + klo;
        floatx4 acc = {0.f, 0.f, 0.f, 0.f};
        #pragma unroll
        for (int s = 0; s < 4; ++s) {
            short8 afrag = *(const short8*)(arow + s * 32);
            acc = __builtin_amdgcn_mfma_f32_16x16x32_bf16(afrag, bfrag[s], acc, 0, 0, 0);
        }
        const int row0 = m * 16 + kg * 4;     // C/D: row = (lane>>4)*4 + reg
        #pragma unroll
        for (int r = 0; r < 4; ++r) {
            float v = acc[r] * 10.0f;
            out[(row0 + r) * OUTC + colw]        = v;
            out[(row0 + r + Bn) * OUTC + colw]   = v;
        }
    }
}

extern "C" void kernel_launch(void* const* d_in, const int* in_sizes, int n_in,
                              void* d_out, int out_size, void* d_ws, size_t ws_size,
                              hipStream_t stream) {
    const float* q      = (const float*)d_in[0];
    const float* k      = (const float*)d_in[1];
    const float* pos    = (const float*)d_in[2];
    const float* negs   = (const float*)d_in[3];
    const float* k_all  = (const float*)d_in[4];
    const float* memory = (const float*)d_in[5];
    const int*   indexp = (const int*)d_in[6];
    float* out = (float*)d_out;
    unsigned short* qb = (unsigned short*)d_ws;   // 512*128*2 = 128 KB

    qconv  <<<64,   256, 0, stream>>>(q, qb);
    poskern<<<128,  256, 0, stream>>>(q, k, pos, out);
    memupd <<<2048, 256, 0, stream>>>(memory, k_all, indexp, out + MEM_OFF);
    gemm_neg<<<NJ / 64, 256, 0, stream>>>(qb, negs, memory, out);
}

// Round 2
// 146.845 us; speedup vs baseline: 1.0929x; 1.0929x over previous
//
#include <hip/hip_runtime.h>

// ---- problem constants ----
constexpr int  Bn    = 512;
constexpr int  Dd    = 128;
constexpr int  QUEUE = 65536;
constexpr int  NEGR  = 8192;              // B*N in-batch negatives
constexpr int  NJ    = NEGR + QUEUE;      // 73728 negative columns
constexpr long long OUTC    = 1 + NJ;     // 73729 out row stride
constexpr long long MEM_OFF = 2LL * Bn * OUTC;  // new_memory offset in d_out

typedef __attribute__((ext_vector_type(8))) short  short8;
typedef __attribute__((ext_vector_type(4))) float  floatx4;

__device__ __forceinline__ unsigned short f2bf(float f) {
    union { float f; unsigned u; } x; x.f = f;
    unsigned u = x.u;
    u += 0x7fffu + ((u >> 16) & 1u);   // round-to-nearest-even
    return (unsigned short)(u >> 16);
}

__device__ __forceinline__ short8 pack8(float4 a, float4 b) {
    short8 r;
    r[0] = (short)f2bf(a.x); r[1] = (short)f2bf(a.y);
    r[2] = (short)f2bf(a.z); r[3] = (short)f2bf(a.w);
    r[4] = (short)f2bf(b.x); r[5] = (short)f2bf(b.y);
    r[6] = (short)f2bf(b.z); r[7] = (short)f2bf(b.w);
    return r;
}

// ---- kernel 0: q (512x128 f32) -> bf16 in workspace ----
__global__ void qconv(const float* __restrict__ q, unsigned short* __restrict__ qb) {
    int t = blockIdx.x * blockDim.x + threadIdx.x;      // 16384 threads, 4 elems each
    float4 v = *(const float4*)(q + (long long)t * 4);
    ushort4 r;
    r.x = f2bf(v.x); r.y = f2bf(v.y); r.z = f2bf(v.z); r.w = f2bf(v.w);
    *(ushort4*)(qb + (long long)t * 4) = r;
}

// ---- kernel 1: positive logits -> out column 0 ----
__global__ void poskern(const float* __restrict__ q, const float* __restrict__ k,
                        const float* __restrict__ ps, float* __restrict__ out) {
    int lane = threadIdx.x & 63;
    int b = blockIdx.x * (blockDim.x >> 6) + (threadIdx.x >> 6);
    if (b >= Bn) return;
    float2 qv = *(const float2*)(q + (long long)b * Dd + lane * 2);
    float2 kv = *(const float2*)(k + (long long)b * Dd + lane * 2);
    float pk = qv.x * kv.x + qv.y * kv.y;
    float pp = 0.f;
    #pragma unroll
    for (int p = 0; p < 4; ++p) {
        float2 pv = *(const float2*)(ps + ((long long)b * 4 + p) * Dd + lane * 2);
        pp += qv.x * pv.x + qv.y * pv.y;
    }
    #pragma unroll
    for (int off = 32; off; off >>= 1) {
        pk += __shfl_xor(pk, off);
        pp += __shfl_xor(pp, off);
    }
    if (lane == 0) {
        out[(long long)b * OUTC]        = pk * 10.0f;
        out[((long long)b + Bn) * OUTC] = (pp * 0.25f) * 10.0f;
    }
}

// ---- kernel 2: new_memory = memory with rows (i+index)%Q <- k_all[i] ----
__global__ void memupd(const float* __restrict__ mem, const float* __restrict__ k_all,
                       const int* __restrict__ indexp, float* __restrict__ outmem) {
    const int index = *indexp;
    const long long total = (long long)QUEUE * (Dd / 4);   // float4 chunks
    long long stride = (long long)gridDim.x * blockDim.x;
    for (long long i = blockIdx.x * (long long)blockDim.x + threadIdx.x; i < total; i += stride) {
        int row = (int)(i >> 5);          // D/4 = 32 chunks per row
        int c4  = (int)(i & 31);
        int src = (row - index) & (QUEUE - 1);
        float4 v;
        if (src < Bn) v = *(const float4*)(k_all + (long long)src * Dd + c4 * 4);
        else          v = *(const float4*)(mem   + (long long)row * Dd + c4 * 4);
        *(float4*)(outmem + (long long)row * Dd + c4 * 4) = v;
    }
}

// ---- kernel 3: l_neg = q @ [negs; memory]^T via bf16 MFMA, written twice, /TEMP ----
// block: 256 threads (4 waves). Each wave owns 16 j-columns; loops 32 M-tiles of 16.
// XCD-aware stripe swizzle: 1152 blocks = 8 XCDs x 144. Adjacent column stripes are
// handled by consecutively-dispatched blocks on the SAME XCD, so the 128B out-lines
// shared at stripe edges (row stride 73729 floats => 4B phase shift per row) get
// assembled in ONE L2 before eviction -> full-line writebacks, no ECC RMW.
__global__ __launch_bounds__(256) void gemm_neg(const unsigned short* __restrict__ qb,
                                                const float* __restrict__ negs,
                                                const float* __restrict__ mem,
                                                float* __restrict__ out) {
    const int lane = threadIdx.x & 63;
    const int wave = threadIdx.x >> 6;
    const int l16  = lane & 15;
    const int kg   = lane >> 4;        // 0..3
    const int klo  = kg * 8;
    const int b    = blockIdx.x;
    const int stripe = (b & 7) * 144 + (b >> 3);       // 1152 = 8 * 144, bijective
    const long long jbase = (long long)stripe * 64 + wave * 16;
    const long long jrow  = jbase + l16;
    const float* src = (jrow < NEGR) ? (negs + jrow * Dd)
                                     : (mem + (jrow - NEGR) * Dd);

    // B fragments for this wave's 16 columns: negmem[j][k], k = klo + s*32 .. +7
    short8 bfrag[4];
    #pragma unroll
    for (int s = 0; s < 4; ++s) {
        float4 x = *(const float4*)(src + s * 32 + klo);
        float4 y = *(const float4*)(src + s * 32 + klo + 4);
        bfrag[s] = pack8(x, y);
    }

    const long long colw = 1 + jbase + l16;   // out column for C-write (col = lane&15)

    #pragma unroll 1
    for (int m = 0; m < 32; ++m) {
        const unsigned short* arow = qb + (long long)(m * 16 + l16) * Dd + klo;
        floatx4 acc = {0.f, 0.f, 0.f, 0.f};
        #pragma unroll
        for (int s = 0; s < 4; ++s) {
            short8 afrag = *(const short8*)(arow + s * 32);
            acc = __builtin_amdgcn_mfma_f32_16x16x32_bf16(afrag, bfrag[s], acc, 0, 0, 0);
        }
        const int row0 = m * 16 + kg * 4;     // C/D: row = (lane>>4)*4 + reg
        #pragma unroll
        for (int r = 0; r < 4; ++r) {
            float v = acc[r] * 10.0f;
            out[(row0 + r) * OUTC + colw]        = v;
            out[(row0 + r + Bn) * OUTC + colw]   = v;
        }
    }
}

extern "C" void kernel_launch(void* const* d_in, const int* in_sizes, int n_in,
                              void* d_out, int out_size, void* d_ws, size_t ws_size,
                              hipStream_t stream) {
    const float* q      = (const float*)d_in[0];
    const float* k      = (const float*)d_in[1];
    const float* pos    = (const float*)d_in[2];
    const float* negs   = (const float*)d_in[3];
    const float* k_all  = (const float*)d_in[4];
    const float* memory = (const float*)d_in[5];
    const int*   indexp = (const int*)d_in[6];
    float* out = (float*)d_out;
    unsigned short* qb = (unsigned short*)d_ws;   // 512*128*2 = 128 KB

    qconv  <<<64,   256, 0, stream>>>(q, qb);
    poskern<<<128,  256, 0, stream>>>(q, k, pos, out);
    memupd <<<2048, 256, 0, stream>>>(memory, k_all, indexp, out + MEM_OFF);
    gemm_neg<<<NJ / 64, 256, 0, stream>>>(qb, negs, memory, out);
}

// Round 3
// 104.315 us; speedup vs baseline: 1.5385x; 1.4077x over previous
//
#include <hip/hip_runtime.h>

// ---- problem constants ----
constexpr int  Bn    = 512;
constexpr int  Dd    = 128;
constexpr int  QUEUE = 65536;
constexpr int  NEGR  = 8192;              // B*N in-batch negatives
constexpr int  NJ    = NEGR + QUEUE;      // 73728 negative columns
constexpr long long OUTC    = 1 + NJ;     // 73729 out row stride
constexpr long long MEM_OFF = 2LL * Bn * OUTC;  // new_memory offset in d_out

// fused-kernel block ranges
constexpr int GEMM_BLK = NJ / 256;        // 288 blocks, 256 cols each
constexpr int POS_BLK  = Bn / 4;          // 128 blocks, 4 rows each (4 waves)
constexpr int MEM_BLK  = 256;             // grid-stride memory-copy blocks
constexpr int TOT_BLK  = GEMM_BLK + POS_BLK + MEM_BLK;

typedef __attribute__((ext_vector_type(8))) short  short8;
typedef __attribute__((ext_vector_type(4))) float  floatx4;

__device__ __forceinline__ unsigned short f2bf(float f) {
    union { float f; unsigned u; } x; x.f = f;
    unsigned u = x.u;
    u += 0x7fffu + ((u >> 16) & 1u);   // round-to-nearest-even
    return (unsigned short)(u >> 16);
}

__device__ __forceinline__ short8 pack8(float4 a, float4 b) {
    short8 r;
    r[0] = (short)f2bf(a.x); r[1] = (short)f2bf(a.y);
    r[2] = (short)f2bf(a.z); r[3] = (short)f2bf(a.w);
    r[4] = (short)f2bf(b.x); r[5] = (short)f2bf(b.y);
    r[6] = (short)f2bf(b.z); r[7] = (short)f2bf(b.w);
    return r;
}

// ---- kernel 0: q (512x128 f32) -> bf16 in workspace (must precede fused kernel) ----
__global__ void qconv(const float* __restrict__ q, unsigned short* __restrict__ qb) {
    int t = blockIdx.x * blockDim.x + threadIdx.x;      // 16384 threads, 4 elems each
    float4 v = *(const float4*)(q + (long long)t * 4);
    ushort4 r;
    r.x = f2bf(v.x); r.y = f2bf(v.y); r.z = f2bf(v.z); r.w = f2bf(v.w);
    *(ushort4*)(qb + (long long)t * 4) = r;
}

// ---- fused kernel: [0,288) gemm | [288,416) positive col | [416,672) memory copy ----
__global__ __launch_bounds__(256) void fused(const unsigned short* __restrict__ qb,
                                             const float* __restrict__ negs,
                                             const float* __restrict__ mem,
                                             const float* __restrict__ q,
                                             const float* __restrict__ k,
                                             const float* __restrict__ ps,
                                             const float* __restrict__ k_all,
                                             const int* __restrict__ indexp,
                                             float* __restrict__ out) {
    const int blk  = blockIdx.x;
    const int lane = threadIdx.x & 63;
    const int wave = threadIdx.x >> 6;

    if (blk < GEMM_BLK) {
        // ---- GEMM: 256 cols/block, 64 cols/wave (4 j-groups of 16) ----
        const int l16 = lane & 15;
        const int kg  = lane >> 4;        // 0..3
        const int klo = kg * 8;
        // XCD swizzle: 288 = 8 * 36 -> adjacent stripes on same XCD's L2
        const int stripe = (blk & 7) * 36 + (blk >> 3);
        const long long jbase = (long long)stripe * 256 + wave * 64;

        // B fragments: 4 j-groups x 4 k-slices; converted f32->bf16 in regs
        short8 bfrag[4][4];
        #pragma unroll
        for (int g = 0; g < 4; ++g) {
            const long long jrow = jbase + g * 16 + l16;
            const float* src = (jrow < NEGR) ? (negs + jrow * Dd)
                                             : (mem + (jrow - NEGR) * Dd);
            #pragma unroll
            for (int s = 0; s < 4; ++s) {
                float4 x = *(const float4*)(src + s * 32 + klo);
                float4 y = *(const float4*)(src + s * 32 + klo + 4);
                bfrag[g][s] = pack8(x, y);
            }
        }

        #pragma unroll 1
        for (int m = 0; m < 32; ++m) {
            const unsigned short* arow = qb + (long long)(m * 16 + l16) * Dd + klo;
            short8 afrag[4];
            #pragma unroll
            for (int s = 0; s < 4; ++s) afrag[s] = *(const short8*)(arow + s * 32);
            const int row0 = m * 16 + kg * 4;     // C/D: row = (lane>>4)*4 + reg
            float* o0 = out + (long long)row0 * OUTC + 1 + jbase + l16;
            #pragma unroll
            for (int g = 0; g < 4; ++g) {
                floatx4 acc = {0.f, 0.f, 0.f, 0.f};
                #pragma unroll
                for (int s = 0; s < 4; ++s)
                    acc = __builtin_amdgcn_mfma_f32_16x16x32_bf16(afrag[s], bfrag[g][s], acc, 0, 0, 0);
                #pragma unroll
                for (int r = 0; r < 4; ++r) {
                    float v = acc[r] * 10.0f;
                    o0[(long long)r * OUTC + g * 16]            = v;
                    o0[((long long)r + Bn) * OUTC + g * 16]     = v;
                }
            }
        }
    } else if (blk < GEMM_BLK + POS_BLK) {
        // ---- positive logits -> out column 0 (one wave per batch row) ----
        const int b = (blk - GEMM_BLK) * 4 + wave;
        float2 qv = *(const float2*)(q + (long long)b * Dd + lane * 2);
        float2 kv = *(const float2*)(k + (long long)b * Dd + lane * 2);
        float pk = qv.x * kv.x + qv.y * kv.y;
        float pp = 0.f;
        #pragma unroll
        for (int p = 0; p < 4; ++p) {
            float2 pv = *(const float2*)(ps + ((long long)b * 4 + p) * Dd + lane * 2);
            pp += qv.x * pv.x + qv.y * pv.y;
        }
        #pragma unroll
        for (int off = 32; off; off >>= 1) {
            pk += __shfl_xor(pk, off);
            pp += __shfl_xor(pp, off);
        }
        if (lane == 0) {
            out[(long long)b * OUTC]        = pk * 10.0f;
            out[((long long)b + Bn) * OUTC] = (pp * 0.25f) * 10.0f;
        }
    } else {
        // ---- new_memory = memory with rows (i+index)%Q <- k_all[i] ----
        float* outmem = out + MEM_OFF;
        const int index = *indexp;
        const long long total = (long long)QUEUE * (Dd / 4);   // float4 chunks
        const long long stride = (long long)MEM_BLK * 256;
        for (long long i = (long long)(blk - GEMM_BLK - POS_BLK) * 256 + threadIdx.x;
             i < total; i += stride) {
            int row = (int)(i >> 5);          // D/4 = 32 chunks per row
            int c4  = (int)(i & 31);
            int src = (row - index) & (QUEUE - 1);
            float4 v;
            if (src < Bn) v = *(const float4*)(k_all + (long long)src * Dd + c4 * 4);
            else          v = *(const float4*)(mem   + (long long)row * Dd + c4 * 4);
            *(float4*)(outmem + (long long)row * Dd + c4 * 4) = v;
        }
    }
}

extern "C" void kernel_launch(void* const* d_in, const int* in_sizes, int n_in,
                              void* d_out, int out_size, void* d_ws, size_t ws_size,
                              hipStream_t stream) {
    const float* q      = (const float*)d_in[0];
    const float* k      = (const float*)d_in[1];
    const float* pos    = (const float*)d_in[2];
    const float* negs   = (const float*)d_in[3];
    const float* k_all  = (const float*)d_in[4];
    const float* memory = (const float*)d_in[5];
    const int*   indexp = (const int*)d_in[6];
    float* out = (float*)d_out;
    unsigned short* qb = (unsigned short*)d_ws;   // 512*128*2 = 128 KB

    qconv<<<64, 256, 0, stream>>>(q, qb);
    fused<<<TOT_BLK, 256, 0, stream>>>(qb, negs, memory, q, k, pos, k_all, indexp, out);
}